// Round 10
// baseline (3153.684 us; speedup 1.0000x reference)
//
#include <hip/hip_runtime.h>
#include <hip/hip_bf16.h>
#include <math.h>

// Problem constants
#define BB 16
#define LL 512
#define DD 512
#define DD2 1024
#define KMIX 8
#define LPAD 520          // L + 8 pad rows (4 each side) for KS=9 conv
#define GRU_KSTEPS 33     // Wp layout keeps 33 k-steps; scan uses 0..31 (bias via scalars)

typedef __attribute__((ext_vector_type(8))) short short8;
typedef __attribute__((ext_vector_type(4))) float f32x4;
typedef unsigned short ushort;

__device__ __forceinline__ float bf2f(ushort u) {
  union { float f; unsigned i; } v; v.i = ((unsigned)u) << 16; return v.f;
}
__device__ __forceinline__ ushort f2bf(float f) {
  union { float f; unsigned i; } v; v.f = f;
  unsigned i = v.i;
  unsigned r = i + 0x7FFF + ((i >> 16) & 1);   // RNE
  return (ushort)(r >> 16);
}

// ---------------------------------------------------------------------------
// Elementwise prep kernels (grid-stride) — unchanged
// ---------------------------------------------------------------------------
__global__ void k_zero_bf16(ushort* p, long n) {
  for (long i = blockIdx.x * 256 + threadIdx.x; i < n; i += (long)gridDim.x * 256) p[i] = 0;
}
__global__ void k_fill_xpad(const float* __restrict__ x, ushort* __restrict__ xp) {
  const long n = (long)BB * LPAD * DD;
  for (long i = blockIdx.x * 256 + threadIdx.x; i < n; i += (long)gridDim.x * 256) {
    int d = (int)(i & 511);
    long rest = i >> 9;
    int p = (int)(rest % LPAD);
    int b = (int)(rest / LPAD);
    float v = 0.f;
    if (p >= 4 && p < 516) v = x[((long)b * LL + (p - 4)) * DD + d];
    xp[i] = f2bf(v);
  }
}
__global__ void k_pack_convw(const float* __restrict__ w, ushort* __restrict__ wp) {
  const long n = (long)DD * DD * 9;
  for (long idx = blockIdx.x * 256 + threadIdx.x; idx < n; idx += (long)gridDim.x * 256) {
    int i = (int)(idx & 511);
    int o = (int)((idx >> 9) & 511);
    int k = (int)(idx >> 18);
    wp[idx] = f2bf(w[((long)o * DD + i) * 9 + k]);
  }
}
__global__ void k_pack_wihx(const float* __restrict__ w_ih, ushort* __restrict__ wp) {
  const long n = (long)3 * DD2 * DD;
  for (long idx = blockIdx.x * 256 + threadIdx.x; idx < n; idx += (long)gridDim.x * 256) {
    int i = (int)(idx & 511);
    int nr = (int)(idx >> 9);
    wp[idx] = f2bf(w_ih[(long)nr * 1536 + i]);
  }
}
__global__ void k_pack_bf16(const float* __restrict__ s, ushort* __restrict__ d, long n) {
  for (long i = blockIdx.x * 256 + threadIdx.x; i < n; i += (long)gridDim.x * 256) d[i] = f2bf(s[i]);
}
__global__ void k_pack_gru(const float* __restrict__ w_ih, const float* __restrict__ w_hh,
                           const float* __restrict__ b_hh, ushort* __restrict__ wp) {
  const long n = (long)64 * 6 * GRU_KSTEPS * 64 * 8;
  for (long idx = blockIdx.x * 256 + threadIdx.x; idx < n; idx += (long)gridDim.x * 256) {
    int j = (int)(idx & 7);
    int lane = (int)((idx >> 3) & 63);
    long r9 = idx >> 9;
    int ks = (int)(r9 % GRU_KSTEPS);
    long tmp = r9 / GRU_KSTEPS;
    int s = (int)(tmp % 6);
    int blk = (int)(tmp / 6);
    int k = ks * 32 + ((lane >> 4) << 3) + j;
    int u = blk * 16 + (lane & 15);
    float v = 0.f;
    if (s < 3) {
      if (k < 1024) v = w_ih[((long)(s * DD2 + u)) * 1536 + 512 + k];
    } else {
      int nr = (s - 3) * DD2 + u;
      if (k < 1024) v = w_hh[(long)nr * DD2 + k];
      else if (k == 1024) v = b_hh[nr];
    }
    wp[idx] = f2bf(v);
  }
}
__global__ void k_init_hbuf(ushort* hb, unsigned* flags) {
  int i = blockIdx.x * 256 + threadIdx.x;
  if (i < 16384) hb[i] = 0;
  if (i < 1024) flags[i] = 0u;
}

// ---------------------------------------------------------------------------
// Generic 128x128 bf16 MFMA GEMM (convs + gi_x only now).
// MODE: 0 +bias->f32 ; 4 +bias->bf16 packed gix [t][ublock][slice][b][u_local]
// ---------------------------------------------------------------------------
template <int MODE, int AMAP>
__global__ __launch_bounds__(256) void gemm128(
    const ushort* __restrict__ A, int lda, long segAoff,
    const ushort* __restrict__ Bt, int ldb, long segBoff,
    int nseg, int kseg, void* __restrict__ Cout, int ldc,
    const float* __restrict__ bias) {
  __shared__ ushort As[128 * 64];
  __shared__ ushort Bs[128 * 64];
  const int tid = threadIdx.x, lane = tid & 63, w = tid >> 6;
  const int wr = w >> 1, wc = w & 1;
  const int m0 = blockIdx.y * 128, n0 = blockIdx.x * 128;

  const ushort* Abase;
  if (AMAP == 1) {
    int b = m0 >> 9, l = m0 & 511;
    Abase = A + ((long)(b * LPAD + l)) * DD;
  } else {
    Abase = A + (long)m0 * lda;
  }
  const ushort* Bbase = Bt + (long)n0 * ldb;

  f32x4 acc[4][4];
#pragma unroll
  for (int i = 0; i < 4; i++)
#pragma unroll
    for (int j = 0; j < 4; j++) acc[i][j] = {0.f, 0.f, 0.f, 0.f};

  for (int seg = 0; seg < nseg; ++seg) {
    const ushort* Aseg = Abase + (long)seg * segAoff;
    const ushort* Bseg = Bbase + (long)seg * segBoff;
    for (int k0 = 0; k0 < kseg; k0 += 64) {
#pragma unroll
      for (int it = 0; it < 4; ++it) {
        int chunk = it * 256 + tid;
        int r = chunk >> 3, cc = chunk & 7;
        int sc = cc ^ (r & 7);
        *(short8*)&As[(size_t)chunk * 8] = *(const short8*)(Aseg + (long)r * lda + k0 + sc * 8);
        *(short8*)&Bs[(size_t)chunk * 8] = *(const short8*)(Bseg + (long)r * ldb + k0 + sc * 8);
      }
      __syncthreads();
#pragma unroll
      for (int kk = 0; kk < 2; ++kk) {
        short8 af[4], bfv[4];
#pragma unroll
        for (int m = 0; m < 4; m++) {
          int row = wr * 64 + m * 16 + (lane & 15);
          int ch = (kk * 4 + (lane >> 4)) ^ (row & 7);
          af[m] = *(const short8*)&As[(size_t)(row * 8 + ch) * 8];
        }
#pragma unroll
        for (int nn = 0; nn < 4; nn++) {
          int row = wc * 64 + nn * 16 + (lane & 15);
          int ch = (kk * 4 + (lane >> 4)) ^ (row & 7);
          bfv[nn] = *(const short8*)&Bs[(size_t)(row * 8 + ch) * 8];
        }
#pragma unroll
        for (int m = 0; m < 4; m++)
#pragma unroll
          for (int nn = 0; nn < 4; nn++)
            acc[m][nn] = __builtin_amdgcn_mfma_f32_16x16x32_bf16(af[m], bfv[nn], acc[m][nn], 0, 0, 0);
      }
      __syncthreads();
    }
  }
  float bvals[4];
#pragma unroll
  for (int nn = 0; nn < 4; nn++) {
    int c = n0 + wc * 64 + nn * 16 + (lane & 15);
    bvals[nn] = bias[c];
  }
#pragma unroll
  for (int m = 0; m < 4; m++) {
    int rbase = m0 + wr * 64 + m * 16 + ((lane >> 4) << 2);
#pragma unroll
    for (int nn = 0; nn < 4; nn++) {
      int c = n0 + wc * 64 + nn * 16 + (lane & 15);
#pragma unroll
      for (int j = 0; j < 4; j++) {
        float v = acc[m][nn][j] + bvals[nn];
        long off = (long)(rbase + j) * ldc + c;
        if (MODE == 0) ((float*)Cout)[off] = v;
        else {
          // MODE 4: packed gix for gru_scan. row=(b*512+t), col=(s*1024+u)
          int r = rbase + j;
          int bb = r >> 9, tt = r & 511, ss = c >> 10, uu = c & 1023;
          long o2 = ((((long)(tt * 64 + (uu >> 4))) * 3 + ss) << 8) + (bb << 4) + (uu & 15);
          ((ushort*)Cout)[o2] = f2bf(v);
        }
      }
    }
  }
}

// ---------------------------------------------------------------------------
// LayerNorm(D=512) + ReLU (unchanged).
// ---------------------------------------------------------------------------
template <int DSTPAD>
__global__ __launch_bounds__(256) void ln_relu(
    const float* __restrict__ y, const float* __restrict__ g,
    const float* __restrict__ be, ushort* __restrict__ dst) {
  const int r = blockIdx.x, tid = threadIdx.x;
  float v0 = y[(long)r * DD + tid];
  float v1 = y[(long)r * DD + 256 + tid];
  float s = v0 + v1, sq = v0 * v0 + v1 * v1;
#pragma unroll
  for (int o = 32; o; o >>= 1) { s += __shfl_down(s, o); sq += __shfl_down(sq, o); }
  __shared__ float red[8];
  int w = tid >> 6, lane = tid & 63;
  if (lane == 0) { red[w] = s; red[4 + w] = sq; }
  __syncthreads();
  if (tid == 0) {
    float ts = 0.f, tq = 0.f;
#pragma unroll
    for (int i = 0; i < 4; i++) { ts += red[i]; tq += red[4 + i]; }
    red[0] = ts; red[1] = tq;
  }
  __syncthreads();
  float mean = red[0] * (1.f / 512.f);
  float var = red[1] * (1.f / 512.f) - mean * mean;
  float rs = rsqrtf(var + 1e-5f);
  long dbase;
  if (DSTPAD) { int b = r >> 9, l = r & 511; dbase = ((long)(b * LPAD + l + 4)) * DD; }
  else dbase = (long)r * DD;
  float o0 = fmaxf(0.f, (v0 - mean) * rs * g[tid] + be[tid]);
  float o1 = fmaxf(0.f, (v1 - mean) * rs * g[tid + 256] + be[tid + 256]);
  dst[dbase + tid] = f2bf(o0);
  dst[dbase + 256 + tid] = f2bf(o1);
}

// ---------------------------------------------------------------------------
// Helpers for the fused kernel
// ---------------------------------------------------------------------------
__device__ __forceinline__ void wait_flags(unsigned need, int tid,
                                           const unsigned* __restrict__ flags) {
  if ((tid >> 6) == 0) {
    while (1) {
      unsigned f = __hip_atomic_load(&flags[(tid & 63) << 4], __ATOMIC_RELAXED,
                                     __HIP_MEMORY_SCOPE_AGENT);
      if (__all((int)(f >= need))) break;
      __builtin_amdgcn_s_sleep(32);
    }
  }
  __syncthreads();
}

// Paired MDN tile: one A-tile (hseq rows m0..m0+127) x two B-tiles (sigma, mu).
// 512 threads = 8 waves, wave grid 2x4 (64x32 C per wave), acc[4][2] per GEMM.
// Accumulation order over k is identical to the old gemm128 -> bitwise-same C.
__device__ void do_pair(int m0, int n0,
                        const ushort* __restrict__ A,
                        const ushort* __restrict__ Bsg, const ushort* __restrict__ Bmu,
                        const float* __restrict__ sg_b, const float* __restrict__ mu_b,
                        float* __restrict__ Cs, float* __restrict__ Cm,
                        char* smem, int tid) {
  ushort* As = (ushort*)smem;            // 16 KB
  ushort* B1 = As + 128 * 64;            // 16 KB (sigma)
  ushort* B2 = B1 + 128 * 64;            // 16 KB (mu)
  const int lane = tid & 63, w = tid >> 6;
  const int wr = w >> 2, wc = w & 3;
  const ushort* Abase = A + (long)m0 * DD2;
  const ushort* Bsb = Bsg + (long)n0 * DD2;
  const ushort* Bmb = Bmu + (long)n0 * DD2;
  f32x4 accS[4][2], accM[4][2];
#pragma unroll
  for (int m = 0; m < 4; m++)
#pragma unroll
    for (int n = 0; n < 2; n++) { accS[m][n] = {0.f,0.f,0.f,0.f}; accM[m][n] = {0.f,0.f,0.f,0.f}; }

  for (int k0 = 0; k0 < DD2; k0 += 64) {
#pragma unroll
    for (int it = 0; it < 2; ++it) {
      int chunk = it * 512 + tid;
      int r = chunk >> 3, cc = chunk & 7, sc = cc ^ (r & 7);
      *(short8*)&As[(size_t)chunk * 8] = *(const short8*)(Abase + (long)r * DD2 + k0 + sc * 8);
      *(short8*)&B1[(size_t)chunk * 8] = *(const short8*)(Bsb + (long)r * DD2 + k0 + sc * 8);
      *(short8*)&B2[(size_t)chunk * 8] = *(const short8*)(Bmb + (long)r * DD2 + k0 + sc * 8);
    }
    __syncthreads();
#pragma unroll
    for (int kk = 0; kk < 2; ++kk) {
      short8 af[4], b1[2], b2[2];
#pragma unroll
      for (int m = 0; m < 4; m++) {
        int row = wr * 64 + m * 16 + (lane & 15);
        int ch = (kk * 4 + (lane >> 4)) ^ (row & 7);
        af[m] = *(const short8*)&As[(size_t)(row * 8 + ch) * 8];
      }
#pragma unroll
      for (int n = 0; n < 2; n++) {
        int row = wc * 32 + n * 16 + (lane & 15);
        int ch = (kk * 4 + (lane >> 4)) ^ (row & 7);
        b1[n] = *(const short8*)&B1[(size_t)(row * 8 + ch) * 8];
        b2[n] = *(const short8*)&B2[(size_t)(row * 8 + ch) * 8];
      }
#pragma unroll
      for (int m = 0; m < 4; m++)
#pragma unroll
        for (int n = 0; n < 2; n++) {
          accS[m][n] = __builtin_amdgcn_mfma_f32_16x16x32_bf16(af[m], b1[n], accS[m][n], 0, 0, 0);
          accM[m][n] = __builtin_amdgcn_mfma_f32_16x16x32_bf16(af[m], b2[n], accM[m][n], 0, 0, 0);
        }
    }
    __syncthreads();
  }
  const int ldc = KMIX * DD2;  // 8192
#pragma unroll
  for (int n = 0; n < 2; n++) {
    const int c = n0 + wc * 32 + n * 16 + (lane & 15);
    const float bs = sg_b[c], bm = mu_b[c];
#pragma unroll
    for (int m = 0; m < 4; m++) {
      const int rbase = m0 + wr * 64 + m * 16 + ((lane >> 4) << 2);
#pragma unroll
      for (int j = 0; j < 4; j++) {
        const long off = (long)(rbase + j) * ldc + c;
        Cs[off] = expf(accS[m][n][j] + bs);
        Cm[off] = accM[m][n][j] + bm;
      }
    }
  }
}

// ---------------------------------------------------------------------------
// Fused persistent kernel: 256 blocks x 512 threads (plain launch).
// Residency/deadlock safety by capacity: launch_bounds(512,4) caps VGPR<=128
// and LDS=48KB -> every CU can host >=2 blocks, so all 256 blocks are
// resident regardless of packing; workers never gate the scan (no cycle).
//   blocks 0-63: v9 GRU scan (verbatim skeleton). h_seq published via relaxed
//     AGENT atomics (write-through to L3) in the same off-critical-path slot;
//     final flag=600 after a drain.
//   blocks 64-255: MDN workers. Paired sigma+mu tiles sharing the A-tile.
//     Gate: rows t<=t0+127 are L3-visible once flag >= t0+129, because
//     h_seq[t] is issued before the syncthreads that precedes flag t+2.
//   tail (t0=384, needs flag>=513): ALL 256 blocks after the scan.
// ---------------------------------------------------------------------------
__global__ __launch_bounds__(512, 4) void fused_scan_mdn(
    const ushort* __restrict__ Wp, const ushort* __restrict__ gix2,
    const float* __restrict__ b_hh,
    ushort* __restrict__ hbuf, ushort* __restrict__ h_seq,
    unsigned* __restrict__ flags,
    const ushort* __restrict__ mdnsg, const ushort* __restrict__ mdnmu,
    const float* __restrict__ sg_b, const float* __restrict__ mu_b,
    float* __restrict__ outS, float* __restrict__ outM) {
  __shared__ char smem[49152];
  const int tid = threadIdx.x;

  if (blockIdx.x < 64) {
    // ------------------------- scan role (v9) -------------------------
    float* red = (float*)smem;
    const int lane = tid & 63, w = tid >> 6, blk = blockIdx.x;
    const int j_c = w;
    const int u_local = lane & 15;
    const int b = ((lane >> 4) << 2) + (j_c & 3);
    const int u = (blk << 4) + u_local;
    const int lanep = ((blk & 1) * 2 + (u_local >> 3)) * 16 + b;
    const long hout_off = ((long)(blk >> 1) * 64 + lanep) * 8 + (u_local & 7);
    const ushort* wpw = Wp + (long)blk * 6 * GRU_KSTEPS * 512 + (long)lane * 8;
    const float bhr = b_hh[u], bhz = b_hh[DD2 + u], bhn = b_hh[2 * DD2 + u];
    float hold = 0.f;

    short8 wr0[4], wr1[4], wr2[4], wr3[4], wr4[4], wr5[4];
#pragma unroll
    for (int i = 0; i < 4; ++i) {
      const int ks = i * 8 + w;
      wr0[i] = *(const short8*)(wpw + (long)(0 * GRU_KSTEPS + ks) * 512);
      wr1[i] = *(const short8*)(wpw + (long)(1 * GRU_KSTEPS + ks) * 512);
      wr2[i] = *(const short8*)(wpw + (long)(2 * GRU_KSTEPS + ks) * 512);
      wr3[i] = *(const short8*)(wpw + (long)(3 * GRU_KSTEPS + ks) * 512);
      wr4[i] = *(const short8*)(wpw + (long)(4 * GRU_KSTEPS + ks) * 512);
      wr5[i] = *(const short8*)(wpw + (long)(5 * GRU_KSTEPS + ks) * 512);
    }

    const int gofs = (b << 4) + u_local;
    for (int t = 0; t < LL; ++t) {
      float gx_r = 0.f, gx_z = 0.f, gx_n = 0.f;
      if (w < 4) {
        const long gbase = ((long)(t * 64 + blk) * 3) << 8;
        gx_r = bf2f(__builtin_nontemporal_load(gix2 + gbase + gofs));
        gx_z = bf2f(__builtin_nontemporal_load(gix2 + gbase + 256 + gofs));
        gx_n = bf2f(__builtin_nontemporal_load(gix2 + gbase + 512 + gofs));
      }
      if (t > 0) {
        if (w == 0) {
          const unsigned tgt = (unsigned)t;
          while (1) {
            unsigned f = __hip_atomic_load(&flags[lane << 4], __ATOMIC_RELAXED,
                                           __HIP_MEMORY_SCOPE_AGENT);
            if (__all((int)(f >= tgt))) break;
            __builtin_amdgcn_s_sleep(1);
          }
        }
        __syncthreads();
      }

      const ushort* hb = hbuf + ((long)t << 14);
      f32x4 acc0 = {0.f,0.f,0.f,0.f}, acc1 = acc0, acc2 = acc0,
            acc3 = acc0, acc4 = acc0, acc5 = acc0;
#pragma unroll
      for (int i = 0; i < 4; ++i) {
        const int ks = i * 8 + w;
        unsigned long long* ap = (unsigned long long*)(hb + (((long)ks * 64 + lane) << 3));
        union { unsigned long long q[2]; short8 v; } cv;
        cv.q[0] = __hip_atomic_load(ap,     __ATOMIC_RELAXED, __HIP_MEMORY_SCOPE_AGENT);
        cv.q[1] = __hip_atomic_load(ap + 1, __ATOMIC_RELAXED, __HIP_MEMORY_SCOPE_AGENT);
        acc0 = __builtin_amdgcn_mfma_f32_16x16x32_bf16(cv.v, wr0[i], acc0, 0, 0, 0);
        acc1 = __builtin_amdgcn_mfma_f32_16x16x32_bf16(cv.v, wr1[i], acc1, 0, 0, 0);
        acc2 = __builtin_amdgcn_mfma_f32_16x16x32_bf16(cv.v, wr2[i], acc2, 0, 0, 0);
        acc3 = __builtin_amdgcn_mfma_f32_16x16x32_bf16(cv.v, wr3[i], acc3, 0, 0, 0);
        acc4 = __builtin_amdgcn_mfma_f32_16x16x32_bf16(cv.v, wr4[i], acc4, 0, 0, 0);
        acc5 = __builtin_amdgcn_mfma_f32_16x16x32_bf16(cv.v, wr5[i], acc5, 0, 0, 0);
      }
#pragma unroll
      for (int j = 0; j < 4; ++j) {
        red[((w * 6 + 0) << 8) + (j << 6) + lane] = acc0[j];
        red[((w * 6 + 1) << 8) + (j << 6) + lane] = acc1[j];
        red[((w * 6 + 2) << 8) + (j << 6) + lane] = acc2[j];
        red[((w * 6 + 3) << 8) + (j << 6) + lane] = acc3[j];
        red[((w * 6 + 4) << 8) + (j << 6) + lane] = acc4[j];
        red[((w * 6 + 5) << 8) + (j << 6) + lane] = acc5[j];
      }
      __syncthreads();
      ushort h16 = 0;
      if (w < 4) {
        float v0 = 0.f, v1 = 0.f, v2 = 0.f, v3 = 0.f, v4 = 0.f, v5 = 0.f;
#pragma unroll
        for (int wv = 0; wv < 8; ++wv) {
          const int base = ((wv * 6) << 8) + (j_c << 6) + lane;
          v0 += red[base];
          v1 += red[base + 256];
          v2 += red[base + 512];
          v3 += red[base + 768];
          v4 += red[base + 1024];
          v5 += red[base + 1280];
        }
        const float rg = 1.f / (1.f + __expf(-(gx_r + v0 + v3 + bhr)));
        const float zg = 1.f / (1.f + __expf(-(gx_z + v1 + v4 + bhz)));
        const float nx = gx_n + v2 + rg * (v5 + bhn);
        const float ng = 1.f - 2.f / (__expf(2.f * nx) + 1.f);
        const float hn = (1.f - zg) * ng + zg * hold;
        hold = hn;
        h16 = f2bf(hn);
      }
      if (t < LL - 1) {
        if (w < 4)
          __hip_atomic_store(hbuf + (((long)(t + 1)) << 14) + hout_off, h16,
                             __ATOMIC_RELAXED, __HIP_MEMORY_SCOPE_AGENT);
        __syncthreads();  // drains vmcnt for every wave before the flag
        if (tid == 0)
          __hip_atomic_store(&flags[blk << 4], (unsigned)(t + 1), __ATOMIC_RELAXED,
                             __HIP_MEMORY_SCOPE_AGENT);
      }
      // h_seq publish: agent-atomic (reaches L3), off the critical path.
      if (w < 4)
        __hip_atomic_store(h_seq + ((long)b * LL + t) * DD2 + u, h16,
                           __ATOMIC_RELAXED, __HIP_MEMORY_SCOPE_AGENT);
    }
    // Final publish: drain h_seq[510..511], then flag=600 (>= any gate).
    __syncthreads();
    if (tid == 0)
      __hip_atomic_store(&flags[blk << 4], 600u, __ATOMIC_RELAXED,
                         __HIP_MEMORY_SCOPE_AGENT);
  } else {
    // ------------------------- worker role -------------------------
    const int wid = blockIdx.x - 64;
    // main pairs: t0 in {0,128,256}; idx = (t0idx*16 + b)*64 + nb
    for (int i = wid; i < 3072; i += 192) {
      const int nb = i & 63;
      const int rest = i >> 6;
      const int b = rest & 15;
      const int t0 = (rest >> 4) * 128;
      wait_flags((unsigned)(t0 + 129), tid, flags);
      do_pair(b * 512 + t0, nb * 128, h_seq, mdnsg, mdnmu, sg_b, mu_b,
              outS, outM, smem, tid);
    }
  }
  // ------------------------- tail (all 256 blocks) -------------------------
  for (int i = blockIdx.x; i < 1024; i += 256) {
    const int nb = i & 63;
    const int b = (i >> 6) & 15;
    wait_flags(513u, tid, flags);
    do_pair(b * 512 + 384, nb * 128, h_seq, mdnsg, mdnmu, sg_b, mu_b,
            outS, outM, smem, tid);
  }
}

// ---------------------------------------------------------------------------
// Mixture-weight head (separate dispatch; kernel boundary = safe visibility).
// ---------------------------------------------------------------------------
__global__ __launch_bounds__(256) void w_head(
    const ushort* __restrict__ h_seq, const float* __restrict__ ww,
    const float* __restrict__ wb, float* __restrict__ out) {
  const int tid = threadIdx.x, lane = tid & 63, w = tid >> 6;
  const long r = (long)blockIdx.x * 4 + w;
  float s[KMIX];
#pragma unroll
  for (int k = 0; k < KMIX; k++) s[k] = 0.f;
  for (int u = lane; u < DD2; u += 64) {
    float hv = bf2f(h_seq[r * DD2 + u]);
#pragma unroll
    for (int k = 0; k < KMIX; k++) s[k] += hv * ww[(long)k * DD2 + u];
  }
#pragma unroll
  for (int k = 0; k < KMIX; k++)
#pragma unroll
    for (int o = 32; o; o >>= 1) s[k] += __shfl_xor(s[k], o);
#pragma unroll
  for (int k = 0; k < KMIX; k++) s[k] += wb[k];
  float m = s[0];
#pragma unroll
  for (int k = 1; k < KMIX; k++) m = fmaxf(m, s[k]);
  float esum = 0.f;
#pragma unroll
  for (int k = 0; k < KMIX; k++) { s[k] = expf(s[k] - m); esum += s[k]; }
  float mine = 0.f;
#pragma unroll
  for (int k = 0; k < KMIX; k++) if (lane == k) mine = s[k];
  if (lane < KMIX) out[r * KMIX + lane] = mine / esum;
}

// ---------------------------------------------------------------------------
extern "C" void kernel_launch(void* const* d_in, const int* in_sizes, int n_in,
                              void* d_out, int out_size, void* d_ws, size_t ws_size,
                              hipStream_t stream) {
  const float* h_text     = (const float*)d_in[0];
  const float* conv1_w    = (const float*)d_in[1];
  const float* conv1_b    = (const float*)d_in[2];
  const float* ln1_g      = (const float*)d_in[3];
  const float* ln1_b      = (const float*)d_in[4];
  const float* conv2_w    = (const float*)d_in[5];
  const float* conv2_b    = (const float*)d_in[6];
  const float* ln2_g      = (const float*)d_in[7];
  const float* ln2_b      = (const float*)d_in[8];
  const float* w_ih       = (const float*)d_in[9];
  const float* w_hh       = (const float*)d_in[10];
  const float* b_ih       = (const float*)d_in[11];
  const float* b_hh       = (const float*)d_in[12];
  const float* mdn_w_w    = (const float*)d_in[13];
  const float* mdn_w_b    = (const float*)d_in[14];
  const float* mdn_sig_w  = (const float*)d_in[15];
  const float* mdn_sig_b  = (const float*)d_in[16];
  const float* mdn_mu_w   = (const float*)d_in[17];
  const float* mdn_mu_b   = (const float*)d_in[18];
  float* out = (float*)d_out;

  char* ws = (char*)d_ws;
  size_t off = 0;
  auto take = [&](size_t bytes) {
    void* p = ws + off;
    off += (bytes + 255) & ~(size_t)255;
    return p;
  };
  ushort* xpad1  = (ushort*)take((size_t)BB * LPAD * DD * 2);
  ushort* xpad2  = (ushort*)take((size_t)BB * LPAD * DD * 2);
  ushort* wpack1 = (ushort*)take((size_t)DD * DD * 9 * 2);
  ushort* wpack2 = (ushort*)take((size_t)DD * DD * 9 * 2);
  float*  ybuf   = (float*) take((size_t)BB * LL * DD * 4);
  ushort* x2     = (ushort*)take((size_t)BB * LL * DD * 2);
  ushort* wihx   = (ushort*)take((size_t)3 * DD2 * DD * 2);
  ushort* gix    = (ushort*)take((size_t)BB * LL * 3 * DD2 * 2);   // packed layout
  ushort* Wp     = (ushort*)take((size_t)64 * 6 * GRU_KSTEPS * 64 * 8 * 2);
  ushort* hseq   = (ushort*)take((size_t)BB * LL * DD2 * 2);
  ushort* mdnmu  = (ushort*)take((size_t)KMIX * DD2 * DD2 * 2);
  ushort* mdnsg  = (ushort*)take((size_t)KMIX * DD2 * DD2 * 2);
  ushort* hbuf   = (ushort*)take((size_t)512 * 16384 * 2);   // 512 write-once frag buffers
  unsigned* flags = (unsigned*)take(64 * 16 * 4);            // 64 flags, 64B-padded lines

  const long sigma_off = (long)BB * LL * KMIX;                    // 65536
  const long mu_off    = sigma_off + (long)BB * LL * KMIX * DD2;  // 67174400

  // --- prep / packing ---
  k_fill_xpad<<<2048, 256, 0, stream>>>(h_text, xpad1);
  k_zero_bf16<<<2048, 256, 0, stream>>>(xpad2, (long)BB * LPAD * DD);
  k_pack_convw<<<2048, 256, 0, stream>>>(conv1_w, wpack1);
  k_pack_convw<<<2048, 256, 0, stream>>>(conv2_w, wpack2);
  k_pack_wihx<<<2048, 256, 0, stream>>>(w_ih, wihx);
  k_pack_gru<<<2048, 256, 0, stream>>>(w_ih, w_hh, b_hh, Wp);
  k_pack_bf16<<<2048, 256, 0, stream>>>(mdn_mu_w, mdnmu, (long)KMIX * DD2 * DD2);
  k_pack_bf16<<<2048, 256, 0, stream>>>(mdn_sig_w, mdnsg, (long)KMIX * DD2 * DD2);
  k_init_hbuf<<<64, 256, 0, stream>>>(hbuf, flags);

  // --- conv block 1: y = conv(xpad1) + b ; LN+ReLU -> xpad2 ---
  gemm128<0, 1><<<dim3(4, 64), 256, 0, stream>>>(xpad1, DD, DD, wpack1, DD, (long)DD * DD, 9, DD,
                                                 ybuf, DD, conv1_b);
  ln_relu<1><<<BB * LL, 256, 0, stream>>>(ybuf, ln1_g, ln1_b, xpad2);

  // --- conv block 2 -> x2 (GRU input, plain bf16 [8192,512]) ---
  gemm128<0, 1><<<dim3(4, 64), 256, 0, stream>>>(xpad2, DD, DD, wpack2, DD, (long)DD * DD, 9, DD,
                                                 ybuf, DD, conv2_b);
  ln_relu<0><<<BB * LL, 256, 0, stream>>>(ybuf, ln2_g, ln2_b, x2);

  // --- gi_x = x2 @ w_ih[:, :512]^T + b_ih -> PACKED gix layout (MODE=4) ---
  gemm128<4, 0><<<dim3(24, 64), 256, 0, stream>>>(x2, DD, 0, wihx, DD, 0, 1, DD,
                                                  gix, 3 * DD2, b_ih);

  // --- fused persistent scan + MDN heads (single dispatch) ---
  fused_scan_mdn<<<256, 512, 0, stream>>>(Wp, gix, b_hh, hbuf, hseq, flags,
                                          mdnsg, mdnmu, mdn_sig_b, mdn_mu_b,
                                          out + sigma_off, out + mu_off);

  // --- mixture weights ---
  w_head<<<BB * LL / 4, 256, 0, stream>>>(hseq, mdn_w_w, mdn_w_b, out);
}

// Round 11
// 1696.073 us; speedup vs baseline: 1.8594x; 1.8594x over previous
//
#include <hip/hip_runtime.h>
#include <hip/hip_bf16.h>
#include <math.h>

// Problem constants
#define BB 16
#define LL 512
#define DD 512
#define DD2 1024
#define KMIX 8
#define LPAD 520          // L + 8 pad rows (4 each side) for KS=9 conv
#define GRU_KSTEPS 33     // Wp layout keeps 33 k-steps; scan uses 0..31 (bias via scalars)

typedef __attribute__((ext_vector_type(8))) short short8;
typedef __attribute__((ext_vector_type(4))) float f32x4;
typedef unsigned short ushort;

__device__ __forceinline__ float bf2f(ushort u) {
  union { float f; unsigned i; } v; v.i = ((unsigned)u) << 16; return v.f;
}
__device__ __forceinline__ ushort f2bf(float f) {
  union { float f; unsigned i; } v; v.f = f;
  unsigned i = v.i;
  unsigned r = i + 0x7FFF + ((i >> 16) & 1);   // RNE
  return (ushort)(r >> 16);
}

// ---------------------------------------------------------------------------
// Elementwise prep kernels (grid-stride) — unchanged
// ---------------------------------------------------------------------------
__global__ void k_zero_bf16(ushort* p, long n) {
  for (long i = blockIdx.x * 256 + threadIdx.x; i < n; i += (long)gridDim.x * 256) p[i] = 0;
}
__global__ void k_fill_xpad(const float* __restrict__ x, ushort* __restrict__ xp) {
  const long n = (long)BB * LPAD * DD;
  for (long i = blockIdx.x * 256 + threadIdx.x; i < n; i += (long)gridDim.x * 256) {
    int d = (int)(i & 511);
    long rest = i >> 9;
    int p = (int)(rest % LPAD);
    int b = (int)(rest / LPAD);
    float v = 0.f;
    if (p >= 4 && p < 516) v = x[((long)b * LL + (p - 4)) * DD + d];
    xp[i] = f2bf(v);
  }
}
__global__ void k_pack_convw(const float* __restrict__ w, ushort* __restrict__ wp) {
  const long n = (long)DD * DD * 9;
  for (long idx = blockIdx.x * 256 + threadIdx.x; idx < n; idx += (long)gridDim.x * 256) {
    int i = (int)(idx & 511);
    int o = (int)((idx >> 9) & 511);
    int k = (int)(idx >> 18);
    wp[idx] = f2bf(w[((long)o * DD + i) * 9 + k]);
  }
}
__global__ void k_pack_wihx(const float* __restrict__ w_ih, ushort* __restrict__ wp) {
  const long n = (long)3 * DD2 * DD;
  for (long idx = blockIdx.x * 256 + threadIdx.x; idx < n; idx += (long)gridDim.x * 256) {
    int i = (int)(idx & 511);
    int nr = (int)(idx >> 9);
    wp[idx] = f2bf(w_ih[(long)nr * 1536 + i]);
  }
}
__global__ void k_pack_bf16(const float* __restrict__ s, ushort* __restrict__ d, long n) {
  for (long i = blockIdx.x * 256 + threadIdx.x; i < n; i += (long)gridDim.x * 256) d[i] = f2bf(s[i]);
}
__global__ void k_pack_gru(const float* __restrict__ w_ih, const float* __restrict__ w_hh,
                           const float* __restrict__ b_hh, ushort* __restrict__ wp) {
  const long n = (long)64 * 6 * GRU_KSTEPS * 64 * 8;
  for (long idx = blockIdx.x * 256 + threadIdx.x; idx < n; idx += (long)gridDim.x * 256) {
    int j = (int)(idx & 7);
    int lane = (int)((idx >> 3) & 63);
    long r9 = idx >> 9;
    int ks = (int)(r9 % GRU_KSTEPS);
    long tmp = r9 / GRU_KSTEPS;
    int s = (int)(tmp % 6);
    int blk = (int)(tmp / 6);
    int k = ks * 32 + ((lane >> 4) << 3) + j;
    int u = blk * 16 + (lane & 15);
    float v = 0.f;
    if (s < 3) {
      if (k < 1024) v = w_ih[((long)(s * DD2 + u)) * 1536 + 512 + k];
    } else {
      int nr = (s - 3) * DD2 + u;
      if (k < 1024) v = w_hh[(long)nr * DD2 + k];
      else if (k == 1024) v = b_hh[nr];
    }
    wp[idx] = f2bf(v);
  }
}
__global__ void k_init_hbuf(ushort* hb, unsigned* flags) {
  int i = blockIdx.x * 256 + threadIdx.x;
  if (i < 16384) hb[i] = 0;
  if (i < 1024) flags[i] = 0u;
}

// ---------------------------------------------------------------------------
// Generic 128x128 bf16 MFMA GEMM (convs + gi_x only now).
// MODE: 0 +bias->f32 ; 4 +bias->bf16 packed gix [t][ublock][slice][b][u_local]
// ---------------------------------------------------------------------------
template <int MODE, int AMAP>
__global__ __launch_bounds__(256) void gemm128(
    const ushort* __restrict__ A, int lda, long segAoff,
    const ushort* __restrict__ Bt, int ldb, long segBoff,
    int nseg, int kseg, void* __restrict__ Cout, int ldc,
    const float* __restrict__ bias) {
  __shared__ ushort As[128 * 64];
  __shared__ ushort Bs[128 * 64];
  const int tid = threadIdx.x, lane = tid & 63, w = tid >> 6;
  const int wr = w >> 1, wc = w & 1;
  const int m0 = blockIdx.y * 128, n0 = blockIdx.x * 128;

  const ushort* Abase;
  if (AMAP == 1) {
    int b = m0 >> 9, l = m0 & 511;
    Abase = A + ((long)(b * LPAD + l)) * DD;
  } else {
    Abase = A + (long)m0 * lda;
  }
  const ushort* Bbase = Bt + (long)n0 * ldb;

  f32x4 acc[4][4];
#pragma unroll
  for (int i = 0; i < 4; i++)
#pragma unroll
    for (int j = 0; j < 4; j++) acc[i][j] = {0.f, 0.f, 0.f, 0.f};

  for (int seg = 0; seg < nseg; ++seg) {
    const ushort* Aseg = Abase + (long)seg * segAoff;
    const ushort* Bseg = Bbase + (long)seg * segBoff;
    for (int k0 = 0; k0 < kseg; k0 += 64) {
#pragma unroll
      for (int it = 0; it < 4; ++it) {
        int chunk = it * 256 + tid;
        int r = chunk >> 3, cc = chunk & 7;
        int sc = cc ^ (r & 7);
        *(short8*)&As[(size_t)chunk * 8] = *(const short8*)(Aseg + (long)r * lda + k0 + sc * 8);
        *(short8*)&Bs[(size_t)chunk * 8] = *(const short8*)(Bseg + (long)r * ldb + k0 + sc * 8);
      }
      __syncthreads();
#pragma unroll
      for (int kk = 0; kk < 2; ++kk) {
        short8 af[4], bfv[4];
#pragma unroll
        for (int m = 0; m < 4; m++) {
          int row = wr * 64 + m * 16 + (lane & 15);
          int ch = (kk * 4 + (lane >> 4)) ^ (row & 7);
          af[m] = *(const short8*)&As[(size_t)(row * 8 + ch) * 8];
        }
#pragma unroll
        for (int nn = 0; nn < 4; nn++) {
          int row = wc * 64 + nn * 16 + (lane & 15);
          int ch = (kk * 4 + (lane >> 4)) ^ (row & 7);
          bfv[nn] = *(const short8*)&Bs[(size_t)(row * 8 + ch) * 8];
        }
#pragma unroll
        for (int m = 0; m < 4; m++)
#pragma unroll
          for (int nn = 0; nn < 4; nn++)
            acc[m][nn] = __builtin_amdgcn_mfma_f32_16x16x32_bf16(af[m], bfv[nn], acc[m][nn], 0, 0, 0);
      }
      __syncthreads();
    }
  }
  float bvals[4];
#pragma unroll
  for (int nn = 0; nn < 4; nn++) {
    int c = n0 + wc * 64 + nn * 16 + (lane & 15);
    bvals[nn] = bias[c];
  }
#pragma unroll
  for (int m = 0; m < 4; m++) {
    int rbase = m0 + wr * 64 + m * 16 + ((lane >> 4) << 2);
#pragma unroll
    for (int nn = 0; nn < 4; nn++) {
      int c = n0 + wc * 64 + nn * 16 + (lane & 15);
#pragma unroll
      for (int j = 0; j < 4; j++) {
        float v = acc[m][nn][j] + bvals[nn];
        long off = (long)(rbase + j) * ldc + c;
        if (MODE == 0) ((float*)Cout)[off] = v;
        else {
          // MODE 4: packed gix for gru_scan. row=(b*512+t), col=(s*1024+u)
          int r = rbase + j;
          int bb = r >> 9, tt = r & 511, ss = c >> 10, uu = c & 1023;
          long o2 = ((((long)(tt * 64 + (uu >> 4))) * 3 + ss) << 8) + (bb << 4) + (uu & 15);
          ((ushort*)Cout)[o2] = f2bf(v);
        }
      }
    }
  }
}

// ---------------------------------------------------------------------------
// LayerNorm(D=512) + ReLU (unchanged).
// ---------------------------------------------------------------------------
template <int DSTPAD>
__global__ __launch_bounds__(256) void ln_relu(
    const float* __restrict__ y, const float* __restrict__ g,
    const float* __restrict__ be, ushort* __restrict__ dst) {
  const int r = blockIdx.x, tid = threadIdx.x;
  float v0 = y[(long)r * DD + tid];
  float v1 = y[(long)r * DD + 256 + tid];
  float s = v0 + v1, sq = v0 * v0 + v1 * v1;
#pragma unroll
  for (int o = 32; o; o >>= 1) { s += __shfl_down(s, o); sq += __shfl_down(sq, o); }
  __shared__ float red[8];
  int w = tid >> 6, lane = tid & 63;
  if (lane == 0) { red[w] = s; red[4 + w] = sq; }
  __syncthreads();
  if (tid == 0) {
    float ts = 0.f, tq = 0.f;
#pragma unroll
    for (int i = 0; i < 4; i++) { ts += red[i]; tq += red[4 + i]; }
    red[0] = ts; red[1] = tq;
  }
  __syncthreads();
  float mean = red[0] * (1.f / 512.f);
  float var = red[1] * (1.f / 512.f) - mean * mean;
  float rs = rsqrtf(var + 1e-5f);
  long dbase;
  if (DSTPAD) { int b = r >> 9, l = r & 511; dbase = ((long)(b * LPAD + l + 4)) * DD; }
  else dbase = (long)r * DD;
  float o0 = fmaxf(0.f, (v0 - mean) * rs * g[tid] + be[tid]);
  float o1 = fmaxf(0.f, (v1 - mean) * rs * g[tid + 256] + be[tid + 256]);
  dst[dbase + tid] = f2bf(o0);
  dst[dbase + 256 + tid] = f2bf(o1);
}

// ---------------------------------------------------------------------------
// Helpers for the fused kernel
// ---------------------------------------------------------------------------
__device__ __forceinline__ void wait_flags(unsigned need, int tid,
                                           const unsigned* __restrict__ flags) {
  // Worker-side gate: COARSE polling (s_sleep(127) ~ 8 us between sweeps) so
  // 192 worker blocks don't storm the scan's flag lines (r10 lesson: poll
  // traffic x pollers serializes the scan's flag stores at L3).
  if ((tid >> 6) == 0) {
    while (1) {
      unsigned f = __hip_atomic_load(&flags[(tid & 63) << 4], __ATOMIC_RELAXED,
                                     __HIP_MEMORY_SCOPE_AGENT);
      if (__all((int)(f >= need))) break;
      __builtin_amdgcn_s_sleep(127);
    }
  }
  __syncthreads();
}

// Paired MDN tile: one A-tile (hseq rows m0..m0+127) x two B-tiles (sigma, mu).
// 512 threads = 8 waves, wave grid 2x4 (64x32 C per wave), acc[4][2] per GEMM.
// Accumulation order over k identical to gemm128 -> bitwise-same C.
__device__ void do_pair(int m0, int n0,
                        const ushort* __restrict__ A,
                        const ushort* __restrict__ Bsg, const ushort* __restrict__ Bmu,
                        const float* __restrict__ sg_b, const float* __restrict__ mu_b,
                        float* __restrict__ Cs, float* __restrict__ Cm,
                        char* smem, int tid) {
  ushort* As = (ushort*)smem;            // 16 KB
  ushort* B1 = As + 128 * 64;            // 16 KB (sigma)
  ushort* B2 = B1 + 128 * 64;            // 16 KB (mu)
  const int lane = tid & 63, w = tid >> 6;
  const int wr = w >> 2, wc = w & 3;
  const ushort* Abase = A + (long)m0 * DD2;
  const ushort* Bsb = Bsg + (long)n0 * DD2;
  const ushort* Bmb = Bmu + (long)n0 * DD2;
  f32x4 accS[4][2], accM[4][2];
#pragma unroll
  for (int m = 0; m < 4; m++)
#pragma unroll
    for (int n = 0; n < 2; n++) { accS[m][n] = {0.f,0.f,0.f,0.f}; accM[m][n] = {0.f,0.f,0.f,0.f}; }

  for (int k0 = 0; k0 < DD2; k0 += 64) {
#pragma unroll
    for (int it = 0; it < 2; ++it) {
      int chunk = it * 512 + tid;
      int r = chunk >> 3, cc = chunk & 7, sc = cc ^ (r & 7);
      *(short8*)&As[(size_t)chunk * 8] = *(const short8*)(Abase + (long)r * DD2 + k0 + sc * 8);
      *(short8*)&B1[(size_t)chunk * 8] = *(const short8*)(Bsb + (long)r * DD2 + k0 + sc * 8);
      *(short8*)&B2[(size_t)chunk * 8] = *(const short8*)(Bmb + (long)r * DD2 + k0 + sc * 8);
    }
    __syncthreads();
#pragma unroll
    for (int kk = 0; kk < 2; ++kk) {
      short8 af[4], b1[2], b2[2];
#pragma unroll
      for (int m = 0; m < 4; m++) {
        int row = wr * 64 + m * 16 + (lane & 15);
        int ch = (kk * 4 + (lane >> 4)) ^ (row & 7);
        af[m] = *(const short8*)&As[(size_t)(row * 8 + ch) * 8];
      }
#pragma unroll
      for (int n = 0; n < 2; n++) {
        int row = wc * 32 + n * 16 + (lane & 15);
        int ch = (kk * 4 + (lane >> 4)) ^ (row & 7);
        b1[n] = *(const short8*)&B1[(size_t)(row * 8 + ch) * 8];
        b2[n] = *(const short8*)&B2[(size_t)(row * 8 + ch) * 8];
      }
#pragma unroll
      for (int m = 0; m < 4; m++)
#pragma unroll
        for (int n = 0; n < 2; n++) {
          accS[m][n] = __builtin_amdgcn_mfma_f32_16x16x32_bf16(af[m], b1[n], accS[m][n], 0, 0, 0);
          accM[m][n] = __builtin_amdgcn_mfma_f32_16x16x32_bf16(af[m], b2[n], accM[m][n], 0, 0, 0);
        }
    }
    __syncthreads();
  }
  const int ldc = KMIX * DD2;  // 8192
#pragma unroll
  for (int n = 0; n < 2; n++) {
    const int c = n0 + wc * 32 + n * 16 + (lane & 15);
    const float bs = sg_b[c], bm = mu_b[c];
#pragma unroll
    for (int m = 0; m < 4; m++) {
      const int rbase = m0 + wr * 64 + m * 16 + ((lane >> 4) << 2);
#pragma unroll
      for (int j = 0; j < 4; j++) {
        const long off = (long)(rbase + j) * ldc + c;
        Cs[off] = expf(accS[m][n][j] + bs);
        Cm[off] = accM[m][n][j] + bm;
      }
    }
  }
}

// ---------------------------------------------------------------------------
// Fused persistent kernel: 256 blocks x 512 threads.
// launch_bounds(512, 2): VGPR/AGPR cap 256/wave -> the scan's 96-VGPR weight
// payload stays register-resident (r10 lesson: the (512,4) 128-cap spilled it,
// VGPR_Count dropped to 64 and the scan tripled). 1 block/CU guaranteed
// resident (LDS 48KB, 8 waves); 256 blocks on 256 CUs -> no deadlock.
//   blocks 0-63: v9 GRU scan (verbatim). h_seq published via relaxed AGENT
//     atomics; final flag=600 after a drain.
//   blocks 64-255: MDN workers, paired sigma+mu tiles sharing the A-tile,
//     gated on flag >= t0+129 (h_seq[t] drained by the syncthreads before
//     flag t+2), COARSE polls.
//   tail (t0=384, gate 513): all 256 blocks after the scan.
// ---------------------------------------------------------------------------
__global__ __launch_bounds__(512, 2) void fused_scan_mdn(
    const ushort* __restrict__ Wp, const ushort* __restrict__ gix2,
    const float* __restrict__ b_hh,
    ushort* __restrict__ hbuf, ushort* __restrict__ h_seq,
    unsigned* __restrict__ flags,
    const ushort* __restrict__ mdnsg, const ushort* __restrict__ mdnmu,
    const float* __restrict__ sg_b, const float* __restrict__ mu_b,
    float* __restrict__ outS, float* __restrict__ outM) {
  __shared__ char smem[49152];
  const int tid = threadIdx.x;

  if (blockIdx.x < 64) {
    // ------------------------- scan role (v9) -------------------------
    float* red = (float*)smem;
    const int lane = tid & 63, w = tid >> 6, blk = blockIdx.x;
    const int j_c = w;
    const int u_local = lane & 15;
    const int b = ((lane >> 4) << 2) + (j_c & 3);
    const int u = (blk << 4) + u_local;
    const int lanep = ((blk & 1) * 2 + (u_local >> 3)) * 16 + b;
    const long hout_off = ((long)(blk >> 1) * 64 + lanep) * 8 + (u_local & 7);
    const ushort* wpw = Wp + (long)blk * 6 * GRU_KSTEPS * 512 + (long)lane * 8;
    const float bhr = b_hh[u], bhz = b_hh[DD2 + u], bhn = b_hh[2 * DD2 + u];
    float hold = 0.f;

    short8 wr0[4], wr1[4], wr2[4], wr3[4], wr4[4], wr5[4];
#pragma unroll
    for (int i = 0; i < 4; ++i) {
      const int ks = i * 8 + w;
      wr0[i] = *(const short8*)(wpw + (long)(0 * GRU_KSTEPS + ks) * 512);
      wr1[i] = *(const short8*)(wpw + (long)(1 * GRU_KSTEPS + ks) * 512);
      wr2[i] = *(const short8*)(wpw + (long)(2 * GRU_KSTEPS + ks) * 512);
      wr3[i] = *(const short8*)(wpw + (long)(3 * GRU_KSTEPS + ks) * 512);
      wr4[i] = *(const short8*)(wpw + (long)(4 * GRU_KSTEPS + ks) * 512);
      wr5[i] = *(const short8*)(wpw + (long)(5 * GRU_KSTEPS + ks) * 512);
    }

    const int gofs = (b << 4) + u_local;
    for (int t = 0; t < LL; ++t) {
      float gx_r = 0.f, gx_z = 0.f, gx_n = 0.f;
      if (w < 4) {
        const long gbase = ((long)(t * 64 + blk) * 3) << 8;
        gx_r = bf2f(__builtin_nontemporal_load(gix2 + gbase + gofs));
        gx_z = bf2f(__builtin_nontemporal_load(gix2 + gbase + 256 + gofs));
        gx_n = bf2f(__builtin_nontemporal_load(gix2 + gbase + 512 + gofs));
      }
      if (t > 0) {
        if (w == 0) {
          const unsigned tgt = (unsigned)t;
          while (1) {
            unsigned f = __hip_atomic_load(&flags[lane << 4], __ATOMIC_RELAXED,
                                           __HIP_MEMORY_SCOPE_AGENT);
            if (__all((int)(f >= tgt))) break;
            __builtin_amdgcn_s_sleep(1);
          }
        }
        __syncthreads();
      }

      const ushort* hb = hbuf + ((long)t << 14);
      f32x4 acc0 = {0.f,0.f,0.f,0.f}, acc1 = acc0, acc2 = acc0,
            acc3 = acc0, acc4 = acc0, acc5 = acc0;
#pragma unroll
      for (int i = 0; i < 4; ++i) {
        const int ks = i * 8 + w;
        unsigned long long* ap = (unsigned long long*)(hb + (((long)ks * 64 + lane) << 3));
        union { unsigned long long q[2]; short8 v; } cv;
        cv.q[0] = __hip_atomic_load(ap,     __ATOMIC_RELAXED, __HIP_MEMORY_SCOPE_AGENT);
        cv.q[1] = __hip_atomic_load(ap + 1, __ATOMIC_RELAXED, __HIP_MEMORY_SCOPE_AGENT);
        acc0 = __builtin_amdgcn_mfma_f32_16x16x32_bf16(cv.v, wr0[i], acc0, 0, 0, 0);
        acc1 = __builtin_amdgcn_mfma_f32_16x16x32_bf16(cv.v, wr1[i], acc1, 0, 0, 0);
        acc2 = __builtin_amdgcn_mfma_f32_16x16x32_bf16(cv.v, wr2[i], acc2, 0, 0, 0);
        acc3 = __builtin_amdgcn_mfma_f32_16x16x32_bf16(cv.v, wr3[i], acc3, 0, 0, 0);
        acc4 = __builtin_amdgcn_mfma_f32_16x16x32_bf16(cv.v, wr4[i], acc4, 0, 0, 0);
        acc5 = __builtin_amdgcn_mfma_f32_16x16x32_bf16(cv.v, wr5[i], acc5, 0, 0, 0);
      }
#pragma unroll
      for (int j = 0; j < 4; ++j) {
        red[((w * 6 + 0) << 8) + (j << 6) + lane] = acc0[j];
        red[((w * 6 + 1) << 8) + (j << 6) + lane] = acc1[j];
        red[((w * 6 + 2) << 8) + (j << 6) + lane] = acc2[j];
        red[((w * 6 + 3) << 8) + (j << 6) + lane] = acc3[j];
        red[((w * 6 + 4) << 8) + (j << 6) + lane] = acc4[j];
        red[((w * 6 + 5) << 8) + (j << 6) + lane] = acc5[j];
      }
      __syncthreads();
      ushort h16 = 0;
      if (w < 4) {
        float v0 = 0.f, v1 = 0.f, v2 = 0.f, v3 = 0.f, v4 = 0.f, v5 = 0.f;
#pragma unroll
        for (int wv = 0; wv < 8; ++wv) {
          const int base = ((wv * 6) << 8) + (j_c << 6) + lane;
          v0 += red[base];
          v1 += red[base + 256];
          v2 += red[base + 512];
          v3 += red[base + 768];
          v4 += red[base + 1024];
          v5 += red[base + 1280];
        }
        const float rg = 1.f / (1.f + __expf(-(gx_r + v0 + v3 + bhr)));
        const float zg = 1.f / (1.f + __expf(-(gx_z + v1 + v4 + bhz)));
        const float nx = gx_n + v2 + rg * (v5 + bhn);
        const float ng = 1.f - 2.f / (__expf(2.f * nx) + 1.f);
        const float hn = (1.f - zg) * ng + zg * hold;
        hold = hn;
        h16 = f2bf(hn);
      }
      if (t < LL - 1) {
        if (w < 4)
          __hip_atomic_store(hbuf + (((long)(t + 1)) << 14) + hout_off, h16,
                             __ATOMIC_RELAXED, __HIP_MEMORY_SCOPE_AGENT);
        __syncthreads();  // drains vmcnt for every wave before the flag
        if (tid == 0)
          __hip_atomic_store(&flags[blk << 4], (unsigned)(t + 1), __ATOMIC_RELAXED,
                             __HIP_MEMORY_SCOPE_AGENT);
      }
      // h_seq publish: agent-atomic (reaches L3), off the critical path.
      if (w < 4)
        __hip_atomic_store(h_seq + ((long)b * LL + t) * DD2 + u, h16,
                           __ATOMIC_RELAXED, __HIP_MEMORY_SCOPE_AGENT);
    }
    // Final publish: drain h_seq[510..511], then flag=600 (>= any gate).
    __syncthreads();
    if (tid == 0)
      __hip_atomic_store(&flags[blk << 4], 600u, __ATOMIC_RELAXED,
                         __HIP_MEMORY_SCOPE_AGENT);
  } else {
    // ------------------------- worker role -------------------------
    const int wid = blockIdx.x - 64;
    // main pairs: t0 in {0,128,256}; idx = (t0idx*16 + b)*64 + nb
    for (int i = wid; i < 3072; i += 192) {
      const int nb = i & 63;
      const int rest = i >> 6;
      const int b = rest & 15;
      const int t0 = (rest >> 4) * 128;
      wait_flags((unsigned)(t0 + 129), tid, flags);
      do_pair(b * 512 + t0, nb * 128, h_seq, mdnsg, mdnmu, sg_b, mu_b,
              outS, outM, smem, tid);
    }
  }
  // ------------------------- tail (all 256 blocks) -------------------------
  for (int i = blockIdx.x; i < 1024; i += 256) {
    const int nb = i & 63;
    const int b = (i >> 6) & 15;
    wait_flags(513u, tid, flags);
    do_pair(b * 512 + 384, nb * 128, h_seq, mdnsg, mdnmu, sg_b, mu_b,
            outS, outM, smem, tid);
  }
}

// ---------------------------------------------------------------------------
// Mixture-weight head (separate dispatch; kernel boundary = safe visibility).
// ---------------------------------------------------------------------------
__global__ __launch_bounds__(256) void w_head(
    const ushort* __restrict__ h_seq, const float* __restrict__ ww,
    const float* __restrict__ wb, float* __restrict__ out) {
  const int tid = threadIdx.x, lane = tid & 63, w = tid >> 6;
  const long r = (long)blockIdx.x * 4 + w;
  float s[KMIX];
#pragma unroll
  for (int k = 0; k < KMIX; k++) s[k] = 0.f;
  for (int u = lane; u < DD2; u += 64) {
    float hv = bf2f(h_seq[r * DD2 + u]);
#pragma unroll
    for (int k = 0; k < KMIX; k++) s[k] += hv * ww[(long)k * DD2 + u];
  }
#pragma unroll
  for (int k = 0; k < KMIX; k++)
#pragma unroll
    for (int o = 32; o; o >>= 1) s[k] += __shfl_xor(s[k], o);
#pragma unroll
  for (int k = 0; k < KMIX; k++) s[k] += wb[k];
  float m = s[0];
#pragma unroll
  for (int k = 1; k < KMIX; k++) m = fmaxf(m, s[k]);
  float esum = 0.f;
#pragma unroll
  for (int k = 0; k < KMIX; k++) { s[k] = expf(s[k] - m); esum += s[k]; }
  float mine = 0.f;
#pragma unroll
  for (int k = 0; k < KMIX; k++) if (lane == k) mine = s[k];
  if (lane < KMIX) out[r * KMIX + lane] = mine / esum;
}

// ---------------------------------------------------------------------------
extern "C" void kernel_launch(void* const* d_in, const int* in_sizes, int n_in,
                              void* d_out, int out_size, void* d_ws, size_t ws_size,
                              hipStream_t stream) {
  const float* h_text     = (const float*)d_in[0];
  const float* conv1_w    = (const float*)d_in[1];
  const float* conv1_b    = (const float*)d_in[2];
  const float* ln1_g      = (const float*)d_in[3];
  const float* ln1_b      = (const float*)d_in[4];
  const float* conv2_w    = (const float*)d_in[5];
  const float* conv2_b    = (const float*)d_in[6];
  const float* ln2_g      = (const float*)d_in[7];
  const float* ln2_b      = (const float*)d_in[8];
  const float* w_ih       = (const float*)d_in[9];
  const float* w_hh       = (const float*)d_in[10];
  const float* b_ih       = (const float*)d_in[11];
  const float* b_hh       = (const float*)d_in[12];
  const float* mdn_w_w    = (const float*)d_in[13];
  const float* mdn_w_b    = (const float*)d_in[14];
  const float* mdn_sig_w  = (const float*)d_in[15];
  const float* mdn_sig_b  = (const float*)d_in[16];
  const float* mdn_mu_w   = (const float*)d_in[17];
  const float* mdn_mu_b   = (const float*)d_in[18];
  float* out = (float*)d_out;

  char* ws = (char*)d_ws;
  size_t off = 0;
  auto take = [&](size_t bytes) {
    void* p = ws + off;
    off += (bytes + 255) & ~(size_t)255;
    return p;
  };
  ushort* xpad1  = (ushort*)take((size_t)BB * LPAD * DD * 2);
  ushort* xpad2  = (ushort*)take((size_t)BB * LPAD * DD * 2);
  ushort* wpack1 = (ushort*)take((size_t)DD * DD * 9 * 2);
  ushort* wpack2 = (ushort*)take((size_t)DD * DD * 9 * 2);
  float*  ybuf   = (float*) take((size_t)BB * LL * DD * 4);
  ushort* x2     = (ushort*)take((size_t)BB * LL * DD * 2);
  ushort* wihx   = (ushort*)take((size_t)3 * DD2 * DD * 2);
  ushort* gix    = (ushort*)take((size_t)BB * LL * 3 * DD2 * 2);   // packed layout
  ushort* Wp     = (ushort*)take((size_t)64 * 6 * GRU_KSTEPS * 64 * 8 * 2);
  ushort* hseq   = (ushort*)take((size_t)BB * LL * DD2 * 2);
  ushort* mdnmu  = (ushort*)take((size_t)KMIX * DD2 * DD2 * 2);
  ushort* mdnsg  = (ushort*)take((size_t)KMIX * DD2 * DD2 * 2);
  ushort* hbuf   = (ushort*)take((size_t)512 * 16384 * 2);   // 512 write-once frag buffers
  unsigned* flags = (unsigned*)take(64 * 16 * 4);            // 64 flags, 64B-padded lines

  const long sigma_off = (long)BB * LL * KMIX;                    // 65536
  const long mu_off    = sigma_off + (long)BB * LL * KMIX * DD2;  // 67174400

  // --- prep / packing ---
  k_fill_xpad<<<2048, 256, 0, stream>>>(h_text, xpad1);
  k_zero_bf16<<<2048, 256, 0, stream>>>(xpad2, (long)BB * LPAD * DD);
  k_pack_convw<<<2048, 256, 0, stream>>>(conv1_w, wpack1);
  k_pack_convw<<<2048, 256, 0, stream>>>(conv2_w, wpack2);
  k_pack_wihx<<<2048, 256, 0, stream>>>(w_ih, wihx);
  k_pack_gru<<<2048, 256, 0, stream>>>(w_ih, w_hh, b_hh, Wp);
  k_pack_bf16<<<2048, 256, 0, stream>>>(mdn_mu_w, mdnmu, (long)KMIX * DD2 * DD2);
  k_pack_bf16<<<2048, 256, 0, stream>>>(mdn_sig_w, mdnsg, (long)KMIX * DD2 * DD2);
  k_init_hbuf<<<64, 256, 0, stream>>>(hbuf, flags);

  // --- conv block 1: y = conv(xpad1) + b ; LN+ReLU -> xpad2 ---
  gemm128<0, 1><<<dim3(4, 64), 256, 0, stream>>>(xpad1, DD, DD, wpack1, DD, (long)DD * DD, 9, DD,
                                                 ybuf, DD, conv1_b);
  ln_relu<1><<<BB * LL, 256, 0, stream>>>(ybuf, ln1_g, ln1_b, xpad2);

  // --- conv block 2 -> x2 (GRU input, plain bf16 [8192,512]) ---
  gemm128<0, 1><<<dim3(4, 64), 256, 0, stream>>>(xpad2, DD, DD, wpack2, DD, (long)DD * DD, 9, DD,
                                                 ybuf, DD, conv2_b);
  ln_relu<0><<<BB * LL, 256, 0, stream>>>(ybuf, ln2_g, ln2_b, x2);

  // --- gi_x = x2 @ w_ih[:, :512]^T + b_ih -> PACKED gix layout (MODE=4) ---
  gemm128<4, 0><<<dim3(24, 64), 256, 0, stream>>>(x2, DD, 0, wihx, DD, 0, 1, DD,
                                                  gix, 3 * DD2, b_ih);

  // --- fused persistent scan + MDN heads (single dispatch) ---
  fused_scan_mdn<<<256, 512, 0, stream>>>(Wp, gix, b_hh, hbuf, hseq, flags,
                                          mdnsg, mdnmu, mdn_sig_b, mdn_mu_b,
                                          out + sigma_off, out + mu_off);

  // --- mixture weights ---
  w_head<<<BB * LL / 4, 256, 0, stream>>>(hseq, mdn_w_w, mdn_w_b, out);
}

// Round 12
// 1681.634 us; speedup vs baseline: 1.8754x; 1.0086x over previous
//
#include <hip/hip_runtime.h>
#include <hip/hip_bf16.h>
#include <math.h>

// Problem constants
#define BB 16
#define LL 512
#define DD 512
#define DD2 1024
#define KMIX 8
#define LPAD 520          // L + 8 pad rows (4 each side) for KS=9 conv
#define GRU_KSTEPS 33     // Wp layout keeps 33 k-steps; scan uses 0..31 (bias via scalars)

typedef __attribute__((ext_vector_type(8))) short short8;
typedef __attribute__((ext_vector_type(4))) float f32x4;
typedef unsigned short ushort;

__device__ __forceinline__ float bf2f(ushort u) {
  union { float f; unsigned i; } v; v.i = ((unsigned)u) << 16; return v.f;
}
__device__ __forceinline__ ushort f2bf(float f) {
  union { float f; unsigned i; } v; v.f = f;
  unsigned i = v.i;
  unsigned r = i + 0x7FFF + ((i >> 16) & 1);   // RNE
  return (ushort)(r >> 16);
}

// ---------------------------------------------------------------------------
// Elementwise prep kernels (grid-stride) — unchanged
// ---------------------------------------------------------------------------
__global__ void k_zero_bf16(ushort* p, long n) {
  for (long i = blockIdx.x * 256 + threadIdx.x; i < n; i += (long)gridDim.x * 256) p[i] = 0;
}
__global__ void k_fill_xpad(const float* __restrict__ x, ushort* __restrict__ xp) {
  const long n = (long)BB * LPAD * DD;
  for (long i = blockIdx.x * 256 + threadIdx.x; i < n; i += (long)gridDim.x * 256) {
    int d = (int)(i & 511);
    long rest = i >> 9;
    int p = (int)(rest % LPAD);
    int b = (int)(rest / LPAD);
    float v = 0.f;
    if (p >= 4 && p < 516) v = x[((long)b * LL + (p - 4)) * DD + d];
    xp[i] = f2bf(v);
  }
}
__global__ void k_pack_convw(const float* __restrict__ w, ushort* __restrict__ wp) {
  const long n = (long)DD * DD * 9;
  for (long idx = blockIdx.x * 256 + threadIdx.x; idx < n; idx += (long)gridDim.x * 256) {
    int i = (int)(idx & 511);
    int o = (int)((idx >> 9) & 511);
    int k = (int)(idx >> 18);
    wp[idx] = f2bf(w[((long)o * DD + i) * 9 + k]);
  }
}
__global__ void k_pack_wihx(const float* __restrict__ w_ih, ushort* __restrict__ wp) {
  const long n = (long)3 * DD2 * DD;
  for (long idx = blockIdx.x * 256 + threadIdx.x; idx < n; idx += (long)gridDim.x * 256) {
    int i = (int)(idx & 511);
    int nr = (int)(idx >> 9);
    wp[idx] = f2bf(w_ih[(long)nr * 1536 + i]);
  }
}
__global__ void k_pack_bf16(const float* __restrict__ s, ushort* __restrict__ d, long n) {
  for (long i = blockIdx.x * 256 + threadIdx.x; i < n; i += (long)gridDim.x * 256) d[i] = f2bf(s[i]);
}
__global__ void k_pack_gru(const float* __restrict__ w_ih, const float* __restrict__ w_hh,
                           const float* __restrict__ b_hh, ushort* __restrict__ wp) {
  const long n = (long)64 * 6 * GRU_KSTEPS * 64 * 8;
  for (long idx = blockIdx.x * 256 + threadIdx.x; idx < n; idx += (long)gridDim.x * 256) {
    int j = (int)(idx & 7);
    int lane = (int)((idx >> 3) & 63);
    long r9 = idx >> 9;
    int ks = (int)(r9 % GRU_KSTEPS);
    long tmp = r9 / GRU_KSTEPS;
    int s = (int)(tmp % 6);
    int blk = (int)(tmp / 6);
    int k = ks * 32 + ((lane >> 4) << 3) + j;
    int u = blk * 16 + (lane & 15);
    float v = 0.f;
    if (s < 3) {
      if (k < 1024) v = w_ih[((long)(s * DD2 + u)) * 1536 + 512 + k];
    } else {
      int nr = (s - 3) * DD2 + u;
      if (k < 1024) v = w_hh[(long)nr * DD2 + k];
      else if (k == 1024) v = b_hh[nr];
    }
    wp[idx] = f2bf(v);
  }
}
__global__ void k_init_hbuf(ushort* hb, unsigned* flags) {
  int i = blockIdx.x * 256 + threadIdx.x;
  if (i < 16384) hb[i] = 0;
  if (i < 1024) flags[i] = 0u;
}

// ---------------------------------------------------------------------------
// Conv GEMM: 64(M)x128(N) tiles, grid (4,128)=512 blocks (2/CU — the old
// 128x128 grid was 256 blocks = 1/CU, grid-limited). K = 9 segs x 512.
// Accumulation order (seg -> k0 -> kk) identical to the old kernel.
// ---------------------------------------------------------------------------
__global__ __launch_bounds__(256) void conv_gemm(
    const ushort* __restrict__ A, const ushort* __restrict__ Bt,
    float* __restrict__ Cout, const float* __restrict__ bias) {
  __shared__ ushort As[64 * 64];    // 8 KB
  __shared__ ushort Bs[128 * 64];   // 16 KB
  const int tid = threadIdx.x, lane = tid & 63, w = tid >> 6;
  const int wr = w >> 1, wc = w & 1;
  const int m0 = blockIdx.y * 64, n0 = blockIdx.x * 128;
  const int b = m0 >> 9, l = m0 & 511;
  const ushort* Abase = A + ((long)(b * LPAD + l)) * DD;
  const ushort* Bbase = Bt + (long)n0 * DD;

  f32x4 acc[2][4];
#pragma unroll
  for (int m = 0; m < 2; m++)
#pragma unroll
    for (int n = 0; n < 4; n++) acc[m][n] = {0.f, 0.f, 0.f, 0.f};

  for (int seg = 0; seg < 9; ++seg) {
    const ushort* Aseg = Abase + (long)seg * DD;
    const ushort* Bseg = Bbase + (long)seg * DD * DD;
    for (int k0 = 0; k0 < DD; k0 += 64) {
#pragma unroll
      for (int it = 0; it < 2; ++it) {
        int chunk = it * 256 + tid;
        int r = chunk >> 3, cc = chunk & 7, sc = cc ^ (r & 7);
        *(short8*)&As[(size_t)chunk * 8] = *(const short8*)(Aseg + (long)r * DD + k0 + sc * 8);
      }
#pragma unroll
      for (int it = 0; it < 4; ++it) {
        int chunk = it * 256 + tid;
        int r = chunk >> 3, cc = chunk & 7, sc = cc ^ (r & 7);
        *(short8*)&Bs[(size_t)chunk * 8] = *(const short8*)(Bseg + (long)r * DD + k0 + sc * 8);
      }
      __syncthreads();
#pragma unroll
      for (int kk = 0; kk < 2; ++kk) {
        short8 af[2], bfv[4];
#pragma unroll
        for (int m = 0; m < 2; m++) {
          int row = wr * 32 + m * 16 + (lane & 15);
          int ch = (kk * 4 + (lane >> 4)) ^ (row & 7);
          af[m] = *(const short8*)&As[(size_t)(row * 8 + ch) * 8];
        }
#pragma unroll
        for (int nn = 0; nn < 4; nn++) {
          int row = wc * 64 + nn * 16 + (lane & 15);
          int ch = (kk * 4 + (lane >> 4)) ^ (row & 7);
          bfv[nn] = *(const short8*)&Bs[(size_t)(row * 8 + ch) * 8];
        }
#pragma unroll
        for (int m = 0; m < 2; m++)
#pragma unroll
          for (int nn = 0; nn < 4; nn++)
            acc[m][nn] = __builtin_amdgcn_mfma_f32_16x16x32_bf16(af[m], bfv[nn], acc[m][nn], 0, 0, 0);
      }
      __syncthreads();
    }
  }
#pragma unroll
  for (int nn = 0; nn < 4; nn++) {
    const int c = n0 + wc * 64 + nn * 16 + (lane & 15);
    const float bv = bias[c];
#pragma unroll
    for (int m = 0; m < 2; m++) {
      const int rbase = m0 + wr * 32 + m * 16 + ((lane >> 4) << 2);
#pragma unroll
      for (int j = 0; j < 4; j++)
        Cout[(long)(rbase + j) * DD + c] = acc[m][nn][j] + bv;
    }
  }
}

// ---------------------------------------------------------------------------
// gi_x GEMM (128x128, MODE4 packed-gix epilogue) — unchanged structure.
// ---------------------------------------------------------------------------
__global__ __launch_bounds__(256) void gix_gemm(
    const ushort* __restrict__ A, const ushort* __restrict__ Bt,
    ushort* __restrict__ Cout, const float* __restrict__ bias) {
  __shared__ ushort As[128 * 64];
  __shared__ ushort Bs[128 * 64];
  const int tid = threadIdx.x, lane = tid & 63, w = tid >> 6;
  const int wr = w >> 1, wc = w & 1;
  const int m0 = blockIdx.y * 128, n0 = blockIdx.x * 128;
  const ushort* Abase = A + (long)m0 * DD;
  const ushort* Bbase = Bt + (long)n0 * DD;

  f32x4 acc[4][4];
#pragma unroll
  for (int i = 0; i < 4; i++)
#pragma unroll
    for (int j = 0; j < 4; j++) acc[i][j] = {0.f, 0.f, 0.f, 0.f};

  for (int k0 = 0; k0 < DD; k0 += 64) {
#pragma unroll
    for (int it = 0; it < 4; ++it) {
      int chunk = it * 256 + tid;
      int r = chunk >> 3, cc = chunk & 7, sc = cc ^ (r & 7);
      *(short8*)&As[(size_t)chunk * 8] = *(const short8*)(Abase + (long)r * DD + k0 + sc * 8);
      *(short8*)&Bs[(size_t)chunk * 8] = *(const short8*)(Bbase + (long)r * DD + k0 + sc * 8);
    }
    __syncthreads();
#pragma unroll
    for (int kk = 0; kk < 2; ++kk) {
      short8 af[4], bfv[4];
#pragma unroll
      for (int m = 0; m < 4; m++) {
        int row = wr * 64 + m * 16 + (lane & 15);
        int ch = (kk * 4 + (lane >> 4)) ^ (row & 7);
        af[m] = *(const short8*)&As[(size_t)(row * 8 + ch) * 8];
      }
#pragma unroll
      for (int nn = 0; nn < 4; nn++) {
        int row = wc * 64 + nn * 16 + (lane & 15);
        int ch = (kk * 4 + (lane >> 4)) ^ (row & 7);
        bfv[nn] = *(const short8*)&Bs[(size_t)(row * 8 + ch) * 8];
      }
#pragma unroll
      for (int m = 0; m < 4; m++)
#pragma unroll
        for (int nn = 0; nn < 4; nn++)
          acc[m][nn] = __builtin_amdgcn_mfma_f32_16x16x32_bf16(af[m], bfv[nn], acc[m][nn], 0, 0, 0);
    }
    __syncthreads();
  }
#pragma unroll
  for (int m = 0; m < 4; m++) {
    int rbase = m0 + wr * 64 + m * 16 + ((lane >> 4) << 2);
#pragma unroll
    for (int nn = 0; nn < 4; nn++) {
      int c = n0 + wc * 64 + nn * 16 + (lane & 15);
      const float bv = bias[c];
#pragma unroll
      for (int j = 0; j < 4; j++) {
        float v = acc[m][nn][j] + bv;
        int r = rbase + j;
        int bb = r >> 9, tt = r & 511, ss = c >> 10, uu = c & 1023;
        long o2 = ((((long)(tt * 64 + (uu >> 4))) * 3 + ss) << 8) + (bb << 4) + (uu & 15);
        Cout[o2] = f2bf(v);
      }
    }
  }
}

// ---------------------------------------------------------------------------
// LayerNorm(D=512) + ReLU (unchanged).
// ---------------------------------------------------------------------------
template <int DSTPAD>
__global__ __launch_bounds__(256) void ln_relu(
    const float* __restrict__ y, const float* __restrict__ g,
    const float* __restrict__ be, ushort* __restrict__ dst) {
  const int r = blockIdx.x, tid = threadIdx.x;
  float v0 = y[(long)r * DD + tid];
  float v1 = y[(long)r * DD + 256 + tid];
  float s = v0 + v1, sq = v0 * v0 + v1 * v1;
#pragma unroll
  for (int o = 32; o; o >>= 1) { s += __shfl_down(s, o); sq += __shfl_down(sq, o); }
  __shared__ float red[8];
  int w = tid >> 6, lane = tid & 63;
  if (lane == 0) { red[w] = s; red[4 + w] = sq; }
  __syncthreads();
  if (tid == 0) {
    float ts = 0.f, tq = 0.f;
#pragma unroll
    for (int i = 0; i < 4; i++) { ts += red[i]; tq += red[4 + i]; }
    red[0] = ts; red[1] = tq;
  }
  __syncthreads();
  float mean = red[0] * (1.f / 512.f);
  float var = red[1] * (1.f / 512.f) - mean * mean;
  float rs = rsqrtf(var + 1e-5f);
  long dbase;
  if (DSTPAD) { int b = r >> 9, l = r & 511; dbase = ((long)(b * LPAD + l + 4)) * DD; }
  else dbase = (long)r * DD;
  float o0 = fmaxf(0.f, (v0 - mean) * rs * g[tid] + be[tid]);
  float o1 = fmaxf(0.f, (v1 - mean) * rs * g[tid + 256] + be[tid + 256]);
  dst[dbase + tid] = f2bf(o0);
  dst[dbase + 256 + tid] = f2bf(o1);
}

// ---------------------------------------------------------------------------
// Helpers for the fused kernel
// ---------------------------------------------------------------------------
__device__ __forceinline__ void wait_flags(unsigned need, int tid,
                                           const unsigned* __restrict__ flags) {
  // COARSE polls (r10 lesson: worker poll traffic serializes scan flag lines).
  if ((tid >> 6) == 0) {
    while (1) {
      unsigned f = __hip_atomic_load(&flags[(tid & 63) << 4], __ATOMIC_RELAXED,
                                     __HIP_MEMORY_SCOPE_AGENT);
      if (__all((int)(f >= need))) break;
      __builtin_amdgcn_s_sleep(127);
    }
  }
  __syncthreads();
}

// Paired MDN tile, MR rows (128 or 64) x 128 cols, sigma+mu share the A-tile.
// MR=128: wave grid 2x4 (64x32 C/wave). MR=64: wave grid 1x8 (64x16 C/wave).
// K-accumulation order identical in both -> bitwise-stable outputs.
template <int MR>
__device__ void do_pair(int m0, int n0,
                        const ushort* __restrict__ A,
                        const ushort* __restrict__ Bsg, const ushort* __restrict__ Bmu,
                        const float* __restrict__ sg_b, const float* __restrict__ mu_b,
                        float* __restrict__ Cs, float* __restrict__ Cm,
                        char* smem, int tid) {
  constexpr int NF = (MR == 128) ? 2 : 1;   // n-frags per wave
  ushort* As = (ushort*)smem;               // MR*64*2 B
  ushort* B1 = As + MR * 64;                // 16 KB (sigma)
  ushort* B2 = B1 + 128 * 64;               // 16 KB (mu)
  const int lane = tid & 63, w = tid >> 6;
  const int wr = (MR == 128) ? (w >> 2) : 0;
  const int wc = (MR == 128) ? (w & 3) : w;
  const ushort* Abase = A + (long)m0 * DD2;
  const ushort* Bsb = Bsg + (long)n0 * DD2;
  const ushort* Bmb = Bmu + (long)n0 * DD2;
  f32x4 accS[4][NF], accM[4][NF];
#pragma unroll
  for (int m = 0; m < 4; m++)
#pragma unroll
    for (int n = 0; n < NF; n++) { accS[m][n] = {0.f,0.f,0.f,0.f}; accM[m][n] = {0.f,0.f,0.f,0.f}; }

  for (int k0 = 0; k0 < DD2; k0 += 64) {
#pragma unroll
    for (int it = 0; it < MR / 64; ++it) {
      int chunk = it * 512 + tid;
      int r = chunk >> 3, cc = chunk & 7, sc = cc ^ (r & 7);
      *(short8*)&As[(size_t)chunk * 8] = *(const short8*)(Abase + (long)r * DD2 + k0 + sc * 8);
    }
#pragma unroll
    for (int it = 0; it < 2; ++it) {
      int chunk = it * 512 + tid;
      int r = chunk >> 3, cc = chunk & 7, sc = cc ^ (r & 7);
      *(short8*)&B1[(size_t)chunk * 8] = *(const short8*)(Bsb + (long)r * DD2 + k0 + sc * 8);
      *(short8*)&B2[(size_t)chunk * 8] = *(const short8*)(Bmb + (long)r * DD2 + k0 + sc * 8);
    }
    __syncthreads();
#pragma unroll
    for (int kk = 0; kk < 2; ++kk) {
      short8 af[4], b1[NF], b2[NF];
#pragma unroll
      for (int m = 0; m < 4; m++) {
        int row = wr * 64 + m * 16 + (lane & 15);
        int ch = (kk * 4 + (lane >> 4)) ^ (row & 7);
        af[m] = *(const short8*)&As[(size_t)(row * 8 + ch) * 8];
      }
#pragma unroll
      for (int n = 0; n < NF; n++) {
        int row = wc * (16 * NF) + n * 16 + (lane & 15);
        int ch = (kk * 4 + (lane >> 4)) ^ (row & 7);
        b1[n] = *(const short8*)&B1[(size_t)(row * 8 + ch) * 8];
        b2[n] = *(const short8*)&B2[(size_t)(row * 8 + ch) * 8];
      }
#pragma unroll
      for (int m = 0; m < 4; m++)
#pragma unroll
        for (int n = 0; n < NF; n++) {
          accS[m][n] = __builtin_amdgcn_mfma_f32_16x16x32_bf16(af[m], b1[n], accS[m][n], 0, 0, 0);
          accM[m][n] = __builtin_amdgcn_mfma_f32_16x16x32_bf16(af[m], b2[n], accM[m][n], 0, 0, 0);
        }
    }
    __syncthreads();
  }
  const int ldc = KMIX * DD2;  // 8192
#pragma unroll
  for (int n = 0; n < NF; n++) {
    const int c = n0 + wc * (16 * NF) + n * 16 + (lane & 15);
    const float bs = sg_b[c], bm = mu_b[c];
#pragma unroll
    for (int m = 0; m < 4; m++) {
      const int rbase = m0 + wr * 64 + m * 16 + ((lane >> 4) << 2);
#pragma unroll
      for (int j = 0; j < 4; j++) {
        const long off = (long)(rbase + j) * ldc + c;
        Cs[off] = expf(accS[m][n][j] + bs);
        Cm[off] = accM[m][n][j] + bm;
      }
    }
  }
}

// ---------------------------------------------------------------------------
// Fused persistent kernel: 256 blocks x 512 threads, launch_bounds(512,2)
// (VGPR cap 256 -> scan's 96-VGPR weight payload stays resident; r10 lesson).
//   blocks 0-63: v9 GRU scan (verbatim). Final flag=600 after full drain.
//   blocks 64-255: MDN workers:
//     main  t0 in {0,128,256}, MR=128, gate t0+129  (flag F => h_seq <= F-2)
//     late  t0=384,            MR=64,  gate 449     (rows 384..447)
//   tail (all 256 blocks): t0=448, MR=64, gate 513 (only the final 600).
//   w_head folded at the end (gate 513), 32 rows/block.
// ---------------------------------------------------------------------------
__global__ __launch_bounds__(512, 2) void fused_scan_mdn(
    const ushort* __restrict__ Wp, const ushort* __restrict__ gix2,
    const float* __restrict__ b_hh,
    ushort* __restrict__ hbuf, ushort* __restrict__ h_seq,
    unsigned* __restrict__ flags,
    const ushort* __restrict__ mdnsg, const ushort* __restrict__ mdnmu,
    const float* __restrict__ sg_b, const float* __restrict__ mu_b,
    float* __restrict__ outS, float* __restrict__ outM,
    const float* __restrict__ ww, const float* __restrict__ wb,
    float* __restrict__ outW) {
  __shared__ char smem[49152];
  const int tid = threadIdx.x;

  if (blockIdx.x < 64) {
    // ------------------------- scan role (v9) -------------------------
    float* red = (float*)smem;
    const int lane = tid & 63, w = tid >> 6, blk = blockIdx.x;
    const int j_c = w;
    const int u_local = lane & 15;
    const int b = ((lane >> 4) << 2) + (j_c & 3);
    const int u = (blk << 4) + u_local;
    const int lanep = ((blk & 1) * 2 + (u_local >> 3)) * 16 + b;
    const long hout_off = ((long)(blk >> 1) * 64 + lanep) * 8 + (u_local & 7);
    const ushort* wpw = Wp + (long)blk * 6 * GRU_KSTEPS * 512 + (long)lane * 8;
    const float bhr = b_hh[u], bhz = b_hh[DD2 + u], bhn = b_hh[2 * DD2 + u];
    float hold = 0.f;

    short8 wr0[4], wr1[4], wr2[4], wr3[4], wr4[4], wr5[4];
#pragma unroll
    for (int i = 0; i < 4; ++i) {
      const int ks = i * 8 + w;
      wr0[i] = *(const short8*)(wpw + (long)(0 * GRU_KSTEPS + ks) * 512);
      wr1[i] = *(const short8*)(wpw + (long)(1 * GRU_KSTEPS + ks) * 512);
      wr2[i] = *(const short8*)(wpw + (long)(2 * GRU_KSTEPS + ks) * 512);
      wr3[i] = *(const short8*)(wpw + (long)(3 * GRU_KSTEPS + ks) * 512);
      wr4[i] = *(const short8*)(wpw + (long)(4 * GRU_KSTEPS + ks) * 512);
      wr5[i] = *(const short8*)(wpw + (long)(5 * GRU_KSTEPS + ks) * 512);
    }

    const int gofs = (b << 4) + u_local;
    for (int t = 0; t < LL; ++t) {
      float gx_r = 0.f, gx_z = 0.f, gx_n = 0.f;
      if (w < 4) {
        const long gbase = ((long)(t * 64 + blk) * 3) << 8;
        gx_r = bf2f(__builtin_nontemporal_load(gix2 + gbase + gofs));
        gx_z = bf2f(__builtin_nontemporal_load(gix2 + gbase + 256 + gofs));
        gx_n = bf2f(__builtin_nontemporal_load(gix2 + gbase + 512 + gofs));
      }
      if (t > 0) {
        if (w == 0) {
          const unsigned tgt = (unsigned)t;
          while (1) {
            unsigned f = __hip_atomic_load(&flags[lane << 4], __ATOMIC_RELAXED,
                                           __HIP_MEMORY_SCOPE_AGENT);
            if (__all((int)(f >= tgt))) break;
            __builtin_amdgcn_s_sleep(1);
          }
        }
        __syncthreads();
      }

      const ushort* hb = hbuf + ((long)t << 14);
      f32x4 acc0 = {0.f,0.f,0.f,0.f}, acc1 = acc0, acc2 = acc0,
            acc3 = acc0, acc4 = acc0, acc5 = acc0;
#pragma unroll
      for (int i = 0; i < 4; ++i) {
        const int ks = i * 8 + w;
        unsigned long long* ap = (unsigned long long*)(hb + (((long)ks * 64 + lane) << 3));
        union { unsigned long long q[2]; short8 v; } cv;
        cv.q[0] = __hip_atomic_load(ap,     __ATOMIC_RELAXED, __HIP_MEMORY_SCOPE_AGENT);
        cv.q[1] = __hip_atomic_load(ap + 1, __ATOMIC_RELAXED, __HIP_MEMORY_SCOPE_AGENT);
        acc0 = __builtin_amdgcn_mfma_f32_16x16x32_bf16(cv.v, wr0[i], acc0, 0, 0, 0);
        acc1 = __builtin_amdgcn_mfma_f32_16x16x32_bf16(cv.v, wr1[i], acc1, 0, 0, 0);
        acc2 = __builtin_amdgcn_mfma_f32_16x16x32_bf16(cv.v, wr2[i], acc2, 0, 0, 0);
        acc3 = __builtin_amdgcn_mfma_f32_16x16x32_bf16(cv.v, wr3[i], acc3, 0, 0, 0);
        acc4 = __builtin_amdgcn_mfma_f32_16x16x32_bf16(cv.v, wr4[i], acc4, 0, 0, 0);
        acc5 = __builtin_amdgcn_mfma_f32_16x16x32_bf16(cv.v, wr5[i], acc5, 0, 0, 0);
      }
#pragma unroll
      for (int j = 0; j < 4; ++j) {
        red[((w * 6 + 0) << 8) + (j << 6) + lane] = acc0[j];
        red[((w * 6 + 1) << 8) + (j << 6) + lane] = acc1[j];
        red[((w * 6 + 2) << 8) + (j << 6) + lane] = acc2[j];
        red[((w * 6 + 3) << 8) + (j << 6) + lane] = acc3[j];
        red[((w * 6 + 4) << 8) + (j << 6) + lane] = acc4[j];
        red[((w * 6 + 5) << 8) + (j << 6) + lane] = acc5[j];
      }
      __syncthreads();
      ushort h16 = 0;
      if (w < 4) {
        float v0 = 0.f, v1 = 0.f, v2 = 0.f, v3 = 0.f, v4 = 0.f, v5 = 0.f;
#pragma unroll
        for (int wv = 0; wv < 8; ++wv) {
          const int base = ((wv * 6) << 8) + (j_c << 6) + lane;
          v0 += red[base];
          v1 += red[base + 256];
          v2 += red[base + 512];
          v3 += red[base + 768];
          v4 += red[base + 1024];
          v5 += red[base + 1280];
        }
        const float rg = 1.f / (1.f + __expf(-(gx_r + v0 + v3 + bhr)));
        const float zg = 1.f / (1.f + __expf(-(gx_z + v1 + v4 + bhz)));
        const float nx = gx_n + v2 + rg * (v5 + bhn);
        const float ng = 1.f - 2.f / (__expf(2.f * nx) + 1.f);
        const float hn = (1.f - zg) * ng + zg * hold;
        hold = hn;
        h16 = f2bf(hn);
      }
      if (t < LL - 1) {
        if (w < 4)
          __hip_atomic_store(hbuf + (((long)(t + 1)) << 14) + hout_off, h16,
                             __ATOMIC_RELAXED, __HIP_MEMORY_SCOPE_AGENT);
        __syncthreads();  // drains vmcnt for every wave before the flag
        if (tid == 0)
          __hip_atomic_store(&flags[blk << 4], (unsigned)(t + 1), __ATOMIC_RELAXED,
                             __HIP_MEMORY_SCOPE_AGENT);
      }
      // h_seq publish: agent-atomic (reaches L3), off the critical path.
      if (w < 4)
        __hip_atomic_store(h_seq + ((long)b * LL + t) * DD2 + u, h16,
                           __ATOMIC_RELAXED, __HIP_MEMORY_SCOPE_AGENT);
    }
    // Final publish: drain h_seq[510..511], then flag=600 (>= any gate).
    __syncthreads();
    if (tid == 0)
      __hip_atomic_store(&flags[blk << 4], 600u, __ATOMIC_RELAXED,
                         __HIP_MEMORY_SCOPE_AGENT);
  } else {
    // ------------------------- worker role -------------------------
    const int wid = blockIdx.x - 64;
    // main pairs: t0 in {0,128,256}
    for (int i = wid; i < 3072; i += 192) {
      const int nb = i & 63;
      const int rest = i >> 6;
      const int b = rest & 15;
      const int t0 = (rest >> 4) * 128;
      wait_flags((unsigned)(t0 + 129), tid, flags);
      do_pair<128>(b * 512 + t0, nb * 128, h_seq, mdnsg, mdnmu, sg_b, mu_b,
                   outS, outM, smem, tid);
    }
    // late pairs: rows 384..447 (MR=64), gated mid-scan at flag 449
    for (int i = wid; i < 1024; i += 192) {
      const int nb = i & 63;
      const int b = (i >> 6) & 15;
      wait_flags(449u, tid, flags);
      do_pair<64>(b * 512 + 384, nb * 128, h_seq, mdnsg, mdnmu, sg_b, mu_b,
                  outS, outM, smem, tid);
    }
  }
  // ------------------------- tail (all 256 blocks): rows 448..511 ----------
  for (int i = blockIdx.x; i < 1024; i += 256) {
    const int nb = i & 63;
    const int b = (i >> 6) & 15;
    wait_flags(513u, tid, flags);
    do_pair<64>(b * 512 + 448, nb * 128, h_seq, mdnsg, mdnmu, sg_b, mu_b,
                outS, outM, smem, tid);
  }
  // ------------------------- w_head fold (all 256 blocks) ------------------
  wait_flags(513u, tid, flags);
  {
    const int lane = tid & 63, w = tid >> 6;
#pragma unroll
    for (int i = 0; i < 4; ++i) {
      const long r = (long)blockIdx.x * 32 + i * 8 + w;
      float s[KMIX];
#pragma unroll
      for (int k = 0; k < KMIX; k++) s[k] = 0.f;
      for (int u = lane; u < DD2; u += 64) {
        float hv = bf2f(h_seq[r * DD2 + u]);
#pragma unroll
        for (int k = 0; k < KMIX; k++) s[k] += hv * ww[(long)k * DD2 + u];
      }
#pragma unroll
      for (int k = 0; k < KMIX; k++)
#pragma unroll
        for (int o = 32; o; o >>= 1) s[k] += __shfl_xor(s[k], o);
#pragma unroll
      for (int k = 0; k < KMIX; k++) s[k] += wb[k];
      float m = s[0];
#pragma unroll
      for (int k = 1; k < KMIX; k++) m = fmaxf(m, s[k]);
      float esum = 0.f;
#pragma unroll
      for (int k = 0; k < KMIX; k++) { s[k] = expf(s[k] - m); esum += s[k]; }
      float mine = 0.f;
#pragma unroll
      for (int k = 0; k < KMIX; k++) if (lane == k) mine = s[k];
      if (lane < KMIX) outW[r * KMIX + lane] = mine / esum;
    }
  }
}

// ---------------------------------------------------------------------------
extern "C" void kernel_launch(void* const* d_in, const int* in_sizes, int n_in,
                              void* d_out, int out_size, void* d_ws, size_t ws_size,
                              hipStream_t stream) {
  const float* h_text     = (const float*)d_in[0];
  const float* conv1_w    = (const float*)d_in[1];
  const float* conv1_b    = (const float*)d_in[2];
  const float* ln1_g      = (const float*)d_in[3];
  const float* ln1_b      = (const float*)d_in[4];
  const float* conv2_w    = (const float*)d_in[5];
  const float* conv2_b    = (const float*)d_in[6];
  const float* ln2_g      = (const float*)d_in[7];
  const float* ln2_b      = (const float*)d_in[8];
  const float* w_ih       = (const float*)d_in[9];
  const float* w_hh       = (const float*)d_in[10];
  const float* b_ih       = (const float*)d_in[11];
  const float* b_hh       = (const float*)d_in[12];
  const float* mdn_w_w    = (const float*)d_in[13];
  const float* mdn_w_b    = (const float*)d_in[14];
  const float* mdn_sig_w  = (const float*)d_in[15];
  const float* mdn_sig_b  = (const float*)d_in[16];
  const float* mdn_mu_w   = (const float*)d_in[17];
  const float* mdn_mu_b   = (const float*)d_in[18];
  float* out = (float*)d_out;

  char* ws = (char*)d_ws;
  size_t off = 0;
  auto take = [&](size_t bytes) {
    void* p = ws + off;
    off += (bytes + 255) & ~(size_t)255;
    return p;
  };
  ushort* xpad1  = (ushort*)take((size_t)BB * LPAD * DD * 2);
  ushort* xpad2  = (ushort*)take((size_t)BB * LPAD * DD * 2);
  ushort* wpack1 = (ushort*)take((size_t)DD * DD * 9 * 2);
  ushort* wpack2 = (ushort*)take((size_t)DD * DD * 9 * 2);
  float*  ybuf   = (float*) take((size_t)BB * LL * DD * 4);
  ushort* x2     = (ushort*)take((size_t)BB * LL * DD * 2);
  ushort* wihx   = (ushort*)take((size_t)3 * DD2 * DD * 2);
  ushort* gix    = (ushort*)take((size_t)BB * LL * 3 * DD2 * 2);   // packed layout
  ushort* Wp     = (ushort*)take((size_t)64 * 6 * GRU_KSTEPS * 64 * 8 * 2);
  ushort* hseq   = (ushort*)take((size_t)BB * LL * DD2 * 2);
  ushort* mdnmu  = (ushort*)take((size_t)KMIX * DD2 * DD2 * 2);
  ushort* mdnsg  = (ushort*)take((size_t)KMIX * DD2 * DD2 * 2);
  ushort* hbuf   = (ushort*)take((size_t)512 * 16384 * 2);   // 512 write-once frag buffers
  unsigned* flags = (unsigned*)take(64 * 16 * 4);            // 64 flags, 64B-padded lines

  const long sigma_off = (long)BB * LL * KMIX;                    // 65536
  const long mu_off    = sigma_off + (long)BB * LL * KMIX * DD2;  // 67174400

  // --- prep / packing ---
  k_fill_xpad<<<2048, 256, 0, stream>>>(h_text, xpad1);
  k_zero_bf16<<<2048, 256, 0, stream>>>(xpad2, (long)BB * LPAD * DD);
  k_pack_convw<<<2048, 256, 0, stream>>>(conv1_w, wpack1);
  k_pack_convw<<<2048, 256, 0, stream>>>(conv2_w, wpack2);
  k_pack_wihx<<<2048, 256, 0, stream>>>(w_ih, wihx);
  k_pack_gru<<<2048, 256, 0, stream>>>(w_ih, w_hh, b_hh, Wp);
  k_pack_bf16<<<2048, 256, 0, stream>>>(mdn_mu_w, mdnmu, (long)KMIX * DD2 * DD2);
  k_pack_bf16<<<2048, 256, 0, stream>>>(mdn_sig_w, mdnsg, (long)KMIX * DD2 * DD2);
  k_init_hbuf<<<64, 256, 0, stream>>>(hbuf, flags);

  // --- conv block 1: y = conv(xpad1) + b ; LN+ReLU -> xpad2 ---
  conv_gemm<<<dim3(4, 128), 256, 0, stream>>>(xpad1, wpack1, ybuf, conv1_b);
  ln_relu<1><<<BB * LL, 256, 0, stream>>>(ybuf, ln1_g, ln1_b, xpad2);

  // --- conv block 2 -> x2 (GRU input, plain bf16 [8192,512]) ---
  conv_gemm<<<dim3(4, 128), 256, 0, stream>>>(xpad2, wpack2, ybuf, conv2_b);
  ln_relu<0><<<BB * LL, 256, 0, stream>>>(ybuf, ln2_g, ln2_b, x2);

  // --- gi_x = x2 @ w_ih[:, :512]^T + b_ih -> PACKED gix layout ---
  gix_gemm<<<dim3(24, 64), 256, 0, stream>>>(x2, wihx, gix, b_ih);

  // --- fused persistent scan + MDN heads + w_head (single dispatch) ---
  fused_scan_mdn<<<256, 512, 0, stream>>>(Wp, gix, b_hh, hbuf, hseq, flags,
                                          mdnsg, mdnmu, mdn_sig_b, mdn_mu_b,
                                          out + sigma_off, out + mu_off,
                                          mdn_w_w, mdn_w_b, out);
}